// Round 1
// baseline (2496.491 us; speedup 1.0000x reference)
//
#include <hip/hip_runtime.h>
#include <math.h>

// Problem constants
#define B_ 256
#define C_ 16
#define I_ 64
#define H_ 40
#define T_ 512
#define G_ 120   // 3*H

#define GRP 8    // batch sequences per block
#define TC  8    // time chunk (gi amortization)

// LDS word strides chosen odd-ish so lane bank residue is 3*k / 27*k -> max 2-way (free)
#define WIH_STRIDE 195   // 64*3 + 3 pad
#define WHH_STRIDE 123   // 40*3 + 3 pad

__device__ __forceinline__ float sigf(float x) {
    return 1.0f / (1.0f + __expf(-x));
}
__device__ __forceinline__ float tanhfast(float x) {
    // tanh(x) = 1 - 2/(exp(2x)+1); handles +-inf saturation correctly in fp32
    float e = __expf(2.0f * x);
    return 1.0f - 2.0f / (e + 1.0f);
}

__global__ __launch_bounds__(320, 2)
void gru_fused_kernel(const float* __restrict__ x,
                      const float* __restrict__ Wih,
                      const float* __restrict__ Whh,
                      const float* __restrict__ bih,
                      const float* __restrict__ bhh,
                      const float* __restrict__ Wfc,
                      const float* __restrict__ bfc,
                      float* __restrict__ out)
{
    __shared__ float wih3[40 * WIH_STRIDE];          // [k][i][3] padded
    __shared__ float whh3[40 * WHH_STRIDE];          // [k][j][3] padded
    __shared__ float xs[GRP * 64 * TC];              // [b][i][t]
    __shared__ float hb[2][GRP][H_];                 // double-buffered hidden

    const int tid = threadIdx.x;
    const int blk = blockIdx.x;
    const int c   = blk >> 5;        // 0..15
    const int bg  = blk & 31;        // 0..31
    const int b0  = bg * GRP;
    const int grp = tid / H_;        // 0..7
    const int k   = tid - grp * H_;  // 0..39
    const int b   = b0 + grp;

    // ---- stage W_ih (gate-triple layout) ----
    const float* wihc = Wih + (size_t)c * G_ * I_;
    for (int idx = tid; idx < 40 * 64; idx += 320) {
        int kk = idx >> 6, ii = idx & 63;
        float r = wihc[(kk)      * 64 + ii];
        float z = wihc[(40 + kk) * 64 + ii];
        float n = wihc[(80 + kk) * 64 + ii];
        float* p = &wih3[kk * WIH_STRIDE + 3 * ii];
        p[0] = r; p[1] = z; p[2] = n;
    }
    // ---- stage W_hh ----
    const float* whhc = Whh + (size_t)c * G_ * H_;
    for (int idx = tid; idx < 40 * 40; idx += 320) {
        int kk = idx / 40, jj = idx - kk * 40;
        float r = whhc[(kk)      * H_ + jj];
        float z = whhc[(40 + kk) * H_ + jj];
        float n = whhc[(80 + kk) * H_ + jj];
        float* p = &whh3[kk * WHH_STRIDE + 3 * jj];
        p[0] = r; p[1] = z; p[2] = n;
    }

    // per-thread biases / fc weight
    const float bir = bih[c * G_ + k];
    const float biz = bih[c * G_ + 40 + k];
    const float bin = bih[c * G_ + 80 + k];
    const float bhr = bhh[c * G_ + k];
    const float bhz = bhh[c * G_ + 40 + k];
    const float bhn = bhh[c * G_ + 80 + k];
    const float wfck = Wfc[c * H_ + k];

    float hreg = 0.0f;
    hb[0][grp][k] = 0.0f;
    hb[1][grp][k] = 0.0f;
    __syncthreads();

    for (int t0 = 0; t0 < T_; t0 += TC) {
        // ---- stage x chunk: GRP b's x 64 i x TC t ----
        for (int idx = tid; idx < GRP * 64 * 2; idx += 320) {
            int tq = idx & 1;
            int ii = (idx >> 1) & 63;
            int bb = idx >> 7;
            size_t gaddr = (((size_t)(b0 + bb) * C_ + c) * I_ + ii) * T_ + t0 + tq * 4;
            const float4 v = *reinterpret_cast<const float4*>(x + gaddr);
            float* d = &xs[(bb * 64 + ii) * TC + tq * 4];
            d[0] = v.x; d[1] = v.y; d[2] = v.z; d[3] = v.w;
        }
        __syncthreads();

        // ---- gi accumulation for TC timesteps (weights read once per i) ----
        float aR[TC], aZ[TC], aN[TC];
        #pragma unroll
        for (int tt = 0; tt < TC; ++tt) { aR[tt] = bir; aZ[tt] = biz; aN[tt] = bin; }
        #pragma unroll 4
        for (int i = 0; i < 64; ++i) {
            const float* wp = &wih3[k * WIH_STRIDE + 3 * i];
            float wr = wp[0], wz = wp[1], wn = wp[2];
            const float* xp = &xs[(grp * 64 + i) * TC];
            #pragma unroll
            for (int tt = 0; tt < TC; ++tt) {
                float xv = xp[tt];
                aR[tt] = fmaf(wr, xv, aR[tt]);
                aZ[tt] = fmaf(wz, xv, aZ[tt]);
                aN[tt] = fmaf(wn, xv, aN[tt]);
            }
        }

        // ---- recurrent steps ----
        #pragma unroll
        for (int tt = 0; tt < TC; ++tt) {
            const int rd = tt & 1;          // cur starts at 0 each chunk (TC even)
            const int wr_ = 1 - rd;
            float hr = bhr, hz = bhz, hn = bhn;
            const float* hp = &hb[rd][grp][0];
            #pragma unroll 4
            for (int j = 0; j < H_; ++j) {
                const float* wp = &whh3[k * WHH_STRIDE + 3 * j];
                float hv = hp[j];
                hr = fmaf(wp[0], hv, hr);
                hz = fmaf(wp[1], hv, hz);
                hn = fmaf(wp[2], hv, hn);
            }
            float r = sigf(aR[tt] + hr);
            float z = sigf(aZ[tt] + hz);
            float n = tanhfast(aN[tt] + r * hn);
            hreg = (1.0f - z) * n + z * hreg;
            hb[wr_][grp][k] = hreg;
            __syncthreads();
        }
    }

    // ---- epilogue: y = sigmoid(W_fc . h + b_fc) ----
    hb[0][grp][k] = hreg * wfck;
    __syncthreads();
    if (k == 0) {
        float s = bfc[c];
        #pragma unroll
        for (int j = 0; j < H_; ++j) s += hb[0][grp][j];
        out[b * C_ + c] = sigf(s);
    }
}

extern "C" void kernel_launch(void* const* d_in, const int* in_sizes, int n_in,
                              void* d_out, int out_size, void* d_ws, size_t ws_size,
                              hipStream_t stream) {
    const float* x   = (const float*)d_in[0];
    const float* Wih = (const float*)d_in[1];
    const float* Whh = (const float*)d_in[2];
    const float* bih = (const float*)d_in[3];
    const float* bhh = (const float*)d_in[4];
    const float* Wfc = (const float*)d_in[5];
    const float* bfc = (const float*)d_in[6];
    float* out = (float*)d_out;

    dim3 grid(C_ * (B_ / GRP));   // 16 * 32 = 512
    dim3 block(GRP * H_);         // 320
    gru_fused_kernel<<<grid, block, 0, stream>>>(x, Wih, Whh, bih, bhh, Wfc, bfc, out);
}

// Round 2
// 962.342 us; speedup vs baseline: 2.5942x; 2.5942x over previous
//
#include <hip/hip_runtime.h>

// Problem constants
#define B_ 256
#define C_ 16
#define I_ 64
#define H_ 40
#define T_ 512
#define G_ 120   // 3*H

#define TT  16          // timesteps per chunk
#define NCH (T_ / TT)   // 32 chunks
#define NT  640         // threads per block (10 waves)

// LDS row strides (element units)
#define SX  72    // xa row stride, bf16 (144 B, 16-aligned, bank-staggered)
#define SG  132   // gi_buf row stride, bf16 (264 B, 8-aligned)
#define SH  132   // gh_buf row stride, fp32 (528 B, 16-aligned)
#define SHB 72    // h_bf16 row stride, bf16

typedef short bf16x8 __attribute__((ext_vector_type(8)));
typedef float f32x4  __attribute__((ext_vector_type(4)));

__device__ __forceinline__ unsigned short f2bf(float f) {
    unsigned u = __float_as_uint(f);
    unsigned r = (u + 0x7FFFu + ((u >> 16) & 1u)) >> 16;   // RNE
    return (unsigned short)r;
}
__device__ __forceinline__ float bf2f(unsigned s) {
    return __uint_as_float(s << 16);
}
__device__ __forceinline__ float sigf(float x) {
    return 1.0f / (1.0f + __expf(-x));
}

__global__ __launch_bounds__(NT, 1)
void gru_mfma_kernel(const float* __restrict__ x,
                     const float* __restrict__ Wih,
                     const float* __restrict__ Whh,
                     const float* __restrict__ bih,
                     const float* __restrict__ bhh,
                     const float* __restrict__ Wfc,
                     const float* __restrict__ bfc,
                     float* __restrict__ out)
{
    // LDS: 36.9 + 67.6 + 8.4 + 2.3 ≈ 115 KB (1 block/CU)
    __shared__ __align__(16) unsigned short xa[256 * SX];      // x chunk, A/B-layout rows m=(t,b)
    __shared__ __align__(16) unsigned short gi_buf[256 * SG];  // gi chunk, bf16 [m][g]
    __shared__ __align__(16) float          gh_buf[16 * SH];   // per-step pre-activations [b][g]
    __shared__ __align__(16) unsigned short hbf[16 * SHB];     // h in bf16 [b][j] (+zero pad j=40..63)

    const int tid = threadIdx.x;
    const int c   = blockIdx.x >> 4;          // channel
    const int b0  = (blockIdx.x & 15) * 16;   // batch base
    const int wav = tid >> 6;
    const int lan = tid & 63;
    const int lq  = lan >> 4;                 // quad 0..3
    const int lm  = lan & 15;

    // R2 (elementwise) mapping: tid = rk*16 + rb  (640 = 40*16 exactly)
    const int rb = tid & 15;
    const int rk = tid >> 4;

    // ---- init h (fp32 master in register, bf16 mirror + zero pad in LDS) ----
    float hreg = 0.0f;
    for (int idx = tid; idx < 16 * SHB; idx += NT) hbf[idx] = 0;

    // ---- load weight fragments into registers (waves 0..7 own gate-tiles) ----
    bf16x8 wihf[2], whhf[2];
    f32x4 bias4 = {0.f, 0.f, 0.f, 0.f};
    if (wav < 8) {
        const int g = wav * 16 + lm;          // A-operand row m = gate index
        #pragma unroll
        for (int ks = 0; ks < 2; ++ks) {
            bf16x8 a, b;
            #pragma unroll
            for (int j = 0; j < 8; ++j) {
                int kk = ks * 32 + lq * 8 + j;
                float wi = (g < G_) ? Wih[((size_t)c * G_ + g) * I_ + kk] : 0.0f;
                float wh = (g < G_ && kk < H_) ? Whh[((size_t)c * G_ + g) * H_ + kk] : 0.0f;
                a[j] = (short)f2bf(wi);
                b[j] = (short)f2bf(wh);
            }
            wihf[ks] = a;
            whhf[ks] = b;
        }
        // bias folded into MFMA accumulator init; D rows g = wav*16 + lq*4 + r
        float bb[4];
        #pragma unroll
        for (int r = 0; r < 4; ++r) {
            int gg = wav * 16 + lq * 4 + r;
            float v = 0.0f;
            if (gg < 80)      v = bih[c * G_ + gg] + bhh[c * G_ + gg]; // r,z: both biases
            else if (gg < G_) v = bhh[c * G_ + gg];                    // n: hh bias only
            bb[r] = v;
        }
        bias4 = {bb[0], bb[1], bb[2], bb[3]};
    }

    // R2 constants
    const float bihn = bih[c * G_ + 80 + rk];
    const float wfck = Wfc[c * H_ + rk];

    // ---- x prefetch machinery: 4096 float4 per chunk, 64B-contiguous per (b,i) ----
    float4 pf[7];
    #define PREFETCH(T0)                                                           \
        {                                                                          \
            _Pragma("unroll")                                                      \
            for (int it = 0; it < 7; ++it) {                                       \
                int idx = tid + it * NT;                                           \
                if (idx < 4096) {                                                  \
                    int q = idx & 3, i = (idx >> 2) & 63, b = idx >> 8;            \
                    const float* p = x + ((((size_t)(b0 + b) * C_ + c) * I_ + i)   \
                                          * T_ + (T0) + q * 4);                    \
                    pf[it] = *reinterpret_cast<const float4*>(p);                  \
                }                                                                  \
            }                                                                      \
        }

    PREFETCH(0);

    for (int ch = 0; ch < NCH; ++ch) {
        // ---- write prefetched x into LDS (rows m = t*16 + b, cols i) ----
        #pragma unroll
        for (int it = 0; it < 7; ++it) {
            int idx = tid + it * NT;
            if (idx < 4096) {
                int q = idx & 3, i = (idx >> 2) & 63, b = idx >> 8;
                float4 v = pf[it];
                xa[((q * 4 + 0) * 16 + b) * SX + i] = f2bf(v.x);
                xa[((q * 4 + 1) * 16 + b) * SX + i] = f2bf(v.y);
                xa[((q * 4 + 2) * 16 + b) * SX + i] = f2bf(v.z);
                xa[((q * 4 + 3) * 16 + b) * SX + i] = f2bf(v.w);
            }
        }
        __syncthreads();

        // ---- gi phase: gi[g][(t,b)] = Wih · x, D rows = 4 consecutive g -> b64 write ----
        if (wav < 8) {
            #pragma unroll 4
            for (int nt = 0; nt < 16; ++nt) {
                const unsigned short* xp = &xa[(nt * 16 + lm) * SX];
                bf16x8 xb0 = *reinterpret_cast<const bf16x8*>(xp + lq * 8);
                bf16x8 xb1 = *reinterpret_cast<const bf16x8*>(xp + 32 + lq * 8);
                f32x4 acc = {0.f, 0.f, 0.f, 0.f};
                acc = __builtin_amdgcn_mfma_f32_16x16x32_bf16(wihf[0], xb0, acc, 0, 0, 0);
                acc = __builtin_amdgcn_mfma_f32_16x16x32_bf16(wihf[1], xb1, acc, 0, 0, 0);
                unsigned lo = (unsigned)f2bf(acc[0]) | ((unsigned)f2bf(acc[1]) << 16);
                unsigned hi = (unsigned)f2bf(acc[2]) | ((unsigned)f2bf(acc[3]) << 16);
                uint2 val; val.x = lo; val.y = hi;
                *reinterpret_cast<uint2*>(&gi_buf[(nt * 16 + lm) * SG + wav * 16 + lq * 4]) = val;
            }
        }
        __syncthreads();

        // ---- prefetch next chunk while recurrent steps run ----
        {
            int tn = (ch + 1 < NCH) ? (ch + 1) * TT : 0;
            PREFETCH(tn);
        }

        // ---- 16 recurrent steps ----
        for (int tt = 0; tt < TT; ++tt) {
            if (wav < 8) {
                const unsigned short* hp = &hbf[lm * SHB];
                bf16x8 h0 = *reinterpret_cast<const bf16x8*>(hp + lq * 8);
                bf16x8 h1 = *reinterpret_cast<const bf16x8*>(hp + 32 + lq * 8);
                f32x4 acc = bias4;
                acc = __builtin_amdgcn_mfma_f32_16x16x32_bf16(whhf[0], h0, acc, 0, 0, 0);
                acc = __builtin_amdgcn_mfma_f32_16x16x32_bf16(whhf[1], h1, acc, 0, 0, 0);
                if (wav < 5) {  // fold gi for r,z gates (g<80; 80 = 5*16 aligns to waves)
                    uint2 gv = *reinterpret_cast<const uint2*>(
                        &gi_buf[(tt * 16 + lm) * SG + wav * 16 + lq * 4]);
                    acc[0] += bf2f(gv.x & 0xffffu);
                    acc[1] += bf2f(gv.x >> 16);
                    acc[2] += bf2f(gv.y & 0xffffu);
                    acc[3] += bf2f(gv.y >> 16);
                }
                *reinterpret_cast<f32x4*>(&gh_buf[lm * SH + wav * 16 + lq * 4]) = acc;
            }
            __syncthreads();

            // R2: gates + h update (all 640 threads, one (b,k) each)
            {
                float pre_r = gh_buf[rb * SH + rk];        // gi_r+gh_r+bih_r+bhh_r
                float pre_z = gh_buf[rb * SH + 40 + rk];   // gi_z+gh_z+bih_z+bhh_z
                float h_n   = gh_buf[rb * SH + 80 + rk];   // gh_n+bhh_n
                float i_n   = bf2f((unsigned)gi_buf[(tt * 16 + rb) * SG + 80 + rk]) + bihn;
                float r = sigf(pre_r);
                float z = sigf(pre_z);
                float nl = i_n + r * h_n;
                float e  = __expf(2.0f * nl);
                float n  = 1.0f - 2.0f / (e + 1.0f);       // tanh
                hreg = (1.0f - z) * n + z * hreg;
                hbf[rb * SHB + rk] = f2bf(hreg);
            }
            __syncthreads();
        }
    }

    // ---- epilogue: y[b,c] = sigmoid(sum_k wfc[k]*h[b,k] + bfc[c]) ----
    float* red = gh_buf;   // reuse (2112 floats >= 640)
    red[tid] = hreg * wfck;
    __syncthreads();
    if (tid < 16) {
        float s = bfc[c];
        #pragma unroll
        for (int k = 0; k < H_; ++k) s += red[k * 16 + tid];
        out[(b0 + tid) * C_ + c] = sigf(s);
    }
}

extern "C" void kernel_launch(void* const* d_in, const int* in_sizes, int n_in,
                              void* d_out, int out_size, void* d_ws, size_t ws_size,
                              hipStream_t stream) {
    const float* x   = (const float*)d_in[0];
    const float* Wih = (const float*)d_in[1];
    const float* Whh = (const float*)d_in[2];
    const float* bih = (const float*)d_in[3];
    const float* bhh = (const float*)d_in[4];
    const float* Wfc = (const float*)d_in[5];
    const float* bfc = (const float*)d_in[6];
    float* out = (float*)d_out;

    dim3 grid(C_ * (B_ / 16));   // 256 blocks = 1/CU
    dim3 block(NT);              // 640 threads = 10 waves
    gru_mfma_kernel<<<grid, block, 0, stream>>>(x, Wih, Whh, bih, bhh, Wfc, bfc, out);
}